// Round 1
// baseline (106.437 us; speedup 1.0000x reference)
//
#include <hip/hip_runtime.h>

// CatNet_76553497084407 — SLAYER-style spiking CNN, fully collapsed over time.
//
// Only spike COUNTS flow between layers, so T=50 is never materialized.
// R8 = R7 (104us bench / 41.8us kernel) + overhead attack, guided by rocprof:
//   * SQ_LDS_BANK_CONFLICT 2.05M cyc == phase-2 window reads at lane-stride-2
//     (4-way). Fix: r1p split into even/odd padded-index arrays -> two
//     stride-1 5-tap reads, conflict-free and ds_read2-mergeable.
//   * spike_rate's exact `c/50.0f` divide (kept for reference-exact rounding)
//     costs ~10 VALU inst x ~19 calls/thread. Replaced by a 51-entry LDS
//     table built ONCE with true divides -> bit-identical result, ~2 inst.
//   * risky-sim threshold 5e-4 -> 2e-4 (fast-vs-sim f32 discrepancy is ~1e-5;
//     10x margin kept). Pooled rate input is 1.1*k/50, k integer: distance to
//     integer >= 0.0011 >> 2e-4, so pooled uses a no-ballot variant.
//   * 1-deep manual LDS-window prefetch in conv2/conv3 ci-loops (compiler held
//     almost nothing in flight at VGPR=32). Copies are static-indexed; live
//     set ~50 regs, below the R4-R6 spill cliff (watch WRITE_SIZE ~8KB).
//   * phase 0 loads float2 (13->7 VMEM/thread); phase 5 dense float2.
// R4-R6 lesson (b128 + full unroll): compiler hoists unrolled LDS loads ->
// >64 live VGPRs -> scratch spills (WRITE_SIZE 190-232MB, 4-6x regression).

#define T_STEPS 50
#define THETA   0.9999f

// Exact-rounding rate: tbl[c] == c/50.0f computed with a true divide once.
__device__ __forceinline__ float spike_rate(float a, const float* __restrict__ tbl) {
    constexpr float INV = 50.0f / 0.9999f;
    float t = a * INV;
    float c = fminf(fmaxf(floorf(t), 0.0f), 50.0f);
    // fall back to the exact 50-step f32 sim when t is near an integer
    bool risky = (t > 0.5f) && (fabsf(t - rintf(t)) < 2e-4f);
    if (__ballot(risky)) {
        float v = 0.f, cnt = 0.f;
#pragma unroll 1
        for (int k = 0; k < T_STEPS; ++k) {
            v += a;
            float s = (v >= THETA) ? 1.0f : 0.0f;
            v -= s * THETA;
            cnt += s;
        }
        c = cnt;
    }
    return tbl[(int)c];
}

// No-ballot variant: only legal when the input provably cannot sit within
// 2e-4 of an integer boundary in t-units (pooled path: 1.1*k/50, margin 1.1e-3).
__device__ __forceinline__ float spike_rate_nb(float a, const float* __restrict__ tbl) {
    constexpr float INV = 50.0f / 0.9999f;
    float t = a * INV;
    float c = fminf(fmaxf(floorf(t), 0.0f), 50.0f);
    return tbl[(int)c];
}

extern "C" __global__ void __launch_bounds__(1024)
catnet_kernel(const float* __restrict__ x,
              const float* __restrict__ w1, const float* __restrict__ b1,
              const float* __restrict__ w2, const float* __restrict__ b2,
              const float* __restrict__ w3, const float* __restrict__ b3,
              const float* __restrict__ wf, const float* __restrict__ bf,
              float* __restrict__ out)
{
    const int n    = blockIdx.x;
    const int tid  = threadIdx.x;
    const int wave = tid >> 6;
    const int lane = tid & 63;

    __shared__ float xbar[182];                  // [h+1], h in [0,180)
    __shared__ float r1pe[16][92];               // even padded-h: H=2i -> [c][i]
    __shared__ float r1po[16][92];               // odd  padded-h: H=2i+1 -> [c][i]
    __shared__ float r3p[32][89];                // [c][h+1], h in [0,87)
    __shared__ alignas(16) float r4s[32][83];
    __shared__ float ratetbl[51];                // exact c/50.0f
    __shared__ float part[16];

    // zero conv pads + build exact-rate table
    if (tid < 16)                { r1pe[tid][0] = 0.f; }            // H=0
    if (tid >= 16 && tid < 32)   { r1po[tid-16][90] = 0.f; }        // H=181
    if (tid >= 32 && tid < 64)   { r3p[tid-32][0] = 0.f; r3p[tid-32][88] = 0.f; }
    if (tid == 64)               { xbar[0] = 0.f; xbar[181] = 0.f; }
    if (tid >= 128 && tid < 179) { ratetbl[tid-128] = (float)(tid-128) / 50.0f; }

    // ---- phase 0: time-sum of input, 4 lanes per h, float2 loads ----
    const float* xn = x + (size_t)n * (180 * 50);
    if (tid < 720) {
        const int h = tid >> 2, q = tid & 3;
        const float2* row2 = reinterpret_cast<const float2*>(xn + h * 50);
        float s = 0.f;
        for (int k = q; k < 24; k += 4) { float2 v = row2[k]; s += v.x + v.y; }
        if (q == 0)                     { float2 v = row2[24]; s += v.x + v.y; }
        s += __shfl_xor(s, 1, 4);
        s += __shfl_xor(s, 2, 4);
        if (q == 0) xbar[h + 1] = s;
    }
    __syncthreads();

    // ---- phase 1: conv1 (1->16, k=3, pad=1), /T, +b1, rate ----
    for (int idx = tid; idx < 16 * 180; idx += 1024) {
        int c = idx / 180, h = idx - c * 180;
        float a = w1[c*3+0] * xbar[h] + w1[c*3+1] * xbar[h+1] + w1[c*3+2] * xbar[h+2];
        a = a / 50.0f + b1[c];
        float r = spike_rate(a, ratetbl);
        int H = h + 1;
        if (H & 1) r1po[c][H >> 1] = r;
        else       r1pe[c][H >> 1] = r;
    }
    __syncthreads();

    // ---- phase 2: conv2 (16->32, k=9, pad=1) + rate + pool(2)*1.1 + rate ----
    // 8 groups of 128 threads: g = tid>>7 (wave-uniform), p = tid&127 < 87.
    // Thread computes conv2 at h=2p,2p+1 (shared 10-tap window) for 4 out-ch.
    // Window tap w[d] (padded H=2p+d): d even -> r1pe[ci][p+d/2],
    //                                  d odd  -> r1po[ci][p+(d-1)/2].
    // Lanes now access stride-1 -> no bank conflicts (was 4-way at stride-2).
    {
        const int g   = __builtin_amdgcn_readfirstlane(tid >> 7);   // 0..7
        const int p   = tid & 127;
        const bool act = p < 87;
        const int pr  = act ? p : 0;
        const float* wb = w2 + g * 4 * 144;   // [j][ci][kh], j stride 144

        float a0[4], a1[4];
#pragma unroll
        for (int j = 0; j < 4; ++j) { a0[j] = b2[g*4 + j]; a1[j] = a0[j]; }

        float we[5], wo[5];
#pragma unroll
        for (int d = 0; d < 5; ++d) { we[d] = r1pe[0][pr + d]; wo[d] = r1po[0][pr + d]; }

#pragma unroll 1
        for (int ci = 0; ci < 16; ++ci) {
            // prefetch next ci's window (clamped: last iter re-reads row 15)
            const int cn = (ci < 15) ? ci + 1 : 15;
            float weN[5], woN[5];
#pragma unroll
            for (int d = 0; d < 5; ++d) { weN[d] = r1pe[cn][pr + d]; woN[d] = r1po[cn][pr + d]; }

#pragma unroll
            for (int j = 0; j < 4; ++j) {
                const float* wj = wb + j * 144 + ci * 9;
#pragma unroll
                for (int kh = 0; kh < 9; ++kh) {
                    float wv  = wj[kh];
                    float xlo = (kh & 1) ? wo[kh >> 1] : we[kh >> 1];        // w[kh]
                    float xhi = (kh & 1) ? we[(kh + 1) >> 1] : wo[kh >> 1];  // w[kh+1]
                    a0[j] += wv * xlo;     // h = 2p
                    a1[j] += wv * xhi;     // h = 2p+1
                }
            }
#pragma unroll
            for (int d = 0; d < 5; ++d) { we[d] = weN[d]; wo[d] = woN[d]; }
        }
#pragma unroll
        for (int j = 0; j < 4; ++j) {
            float r20 = spike_rate(a0[j], ratetbl);
            float r21 = spike_rate(a1[j], ratetbl);
            float r3  = spike_rate_nb(1.1f * (r20 + r21), ratetbl);
            if (act) r3p[g*4 + j][p + 1] = r3;
        }
    }
    __syncthreads();

    // ---- phase 4: conv3 (32->32, k=7, pad=1) + rate ----
    // 16 waves = 8 out-ch-groups(4) x 2 h-halves; lanes -> h. 1-deep prefetch.
    {
        const int g4   = __builtin_amdgcn_readfirstlane((wave >> 1) * 4);
        const int half = wave & 1;
        const int cnt  = half ? 41 : 42;
        const bool act = lane < cnt;
        const int h0   = half * 42 + lane;    // valid max 82; window max 88
        const int hr   = act ? h0 : 0;
        const float* wb = w3 + g4 * 224;      // [j][ci][kh], j stride 224

        float a[4];
#pragma unroll
        for (int j = 0; j < 4; ++j) a[j] = b3[g4 + j];

        float rv[7];
#pragma unroll
        for (int kh = 0; kh < 7; ++kh) rv[kh] = r3p[0][hr + kh];

#pragma unroll 1
        for (int ci = 0; ci < 32; ++ci) {
            const int cn = (ci < 31) ? ci + 1 : 31;
            float rn[7];
#pragma unroll
            for (int kh = 0; kh < 7; ++kh) rn[kh] = r3p[cn][hr + kh];

#pragma unroll
            for (int j = 0; j < 4; ++j) {
                const float* wj = wb + j * 224 + ci * 7;
#pragma unroll
                for (int kh = 0; kh < 7; ++kh)
                    a[j] += wj[kh] * rv[kh];
            }
#pragma unroll
            for (int kh = 0; kh < 7; ++kh) rv[kh] = rn[kh];
        }
#pragma unroll
        for (int j = 0; j < 4; ++j) {
            float r = spike_rate(a[j], ratetbl);
            if (act) r4s[g4 + j][h0] = r;
        }
    }
    __syncthreads();

    // ---- phase 5: dense [32*83] -> 4 outputs; 4 waves per output, float2 ----
    {
        const int o = wave >> 2, q = wave & 3;
        const float2* r42 = reinterpret_cast<const float2*>(&r4s[0][0]);
        const float2* wo2 = reinterpret_cast<const float2*>(wf + o * (32 * 83));
        float acc = 0.f;
        for (int j = q * 64 + lane; j < 1328; j += 256) {
            float2 rv = r42[j], wv = wo2[j];
            acc += rv.x * wv.x + rv.y * wv.y;
        }
#pragma unroll
        for (int off = 32; off > 0; off >>= 1)
            acc += __shfl_down(acc, off, 64);
        if (lane == 0) part[wave] = acc;
    }
    __syncthreads();
    if (tid < 4) {
        float s = part[tid*4] + part[tid*4+1] + part[tid*4+2] + part[tid*4+3];
        out[n * 4 + tid] = s + bf[tid];
    }
}

extern "C" void kernel_launch(void* const* d_in, const int* in_sizes, int n_in,
                              void* d_out, int out_size, void* d_ws, size_t ws_size,
                              hipStream_t stream) {
    const float* x  = (const float*)d_in[0];
    const float* w1 = (const float*)d_in[1];
    const float* b1 = (const float*)d_in[2];
    const float* w2 = (const float*)d_in[3];
    const float* b2 = (const float*)d_in[4];
    const float* w3 = (const float*)d_in[5];
    const float* b3 = (const float*)d_in[6];
    const float* wf = (const float*)d_in[7];
    const float* bf = (const float*)d_in[8];
    float* outp = (float*)d_out;

    catnet_kernel<<<dim3(256), dim3(1024), 0, stream>>>(
        x, w1, b1, w2, b2, w3, b3, wf, bf, outp);
}